// Round 2
// baseline (165.599 us; speedup 1.0000x reference)
//
#include <hip/hip_runtime.h>
#include <hip/hip_bf16.h>

// ClusterLoss fused kernel for MI355X (gfx950).
// N=131072 features [N,128] fp32, K=1024 centers [K,128] fp32.
// loss = mean_n || f_n - c_{a(n)} ||^2,  f = l2norm(features),
// a(n) = argmax_k f_n . l2norm(c_k)  ==  argmax_k feat_n . chat_k
// loss_n = 1 - 2*d*||c_a||/||feat_n|| + ||c_a||^2  with d = feat_n . chat_a
//
// Strategy: bf16 MFMA (16x16x32) GEMM with fused per-row argmax; sims never
// materialized. Loss scalars computed in fp32.
// R1 bug: per-wave argmax only covered one column half (wn), yet both wn
// waves emitted loss for the same rows -> out ~= 2x ref. R2 adds the
// cross-wn LDS reduction before the loss epilogue.

#define D 128
#define BM 128
#define BN 128
#define LSTR 136   // LDS row stride in bf16 elems (272 B): 16B pad breaks bank aliasing

typedef __attribute__((ext_vector_type(4))) float floatx4;
typedef __attribute__((ext_vector_type(8))) short shortx8;
typedef __attribute__((ext_vector_type(4))) short shortx4;

__device__ __forceinline__ unsigned short f32_to_bf16_rne(float x) {
    unsigned int u = __builtin_bit_cast(unsigned int, x);
    unsigned int r = (u + 0x7FFFu + ((u >> 16) & 1u)) >> 16;
    return (unsigned short)r;
}

// ---- Prep: normalize centers -> bf16 chat, store fp32 norms; zero d_out ----
__global__ void prep_centers(const float* __restrict__ centers,
                             unsigned short* __restrict__ chat,
                             float* __restrict__ cnorm,
                             float* __restrict__ out) {
    const int k = blockIdx.x;
    const int t = threadIdx.x;            // 128 threads, one per dim
    float v = centers[(size_t)k * D + t];
    float s = v * v;
    #pragma unroll
    for (int m = 1; m <= 32; m <<= 1) s += __shfl_xor(s, m);   // 64-lane sum
    __shared__ float ws2[2];
    if ((t & 63) == 0) ws2[t >> 6] = s;
    __syncthreads();
    float total = ws2[0] + ws2[1];
    float n = sqrtf(total);
    float neff = fmaxf(n, 1e-12f);
    chat[(size_t)k * D + t] = f32_to_bf16_rne(v / neff);
    if (t == 0) cnorm[k] = n;
    if (k == 0 && t == 0) out[0] = 0.0f;   // runs before main kernel on stream
}

// ---- Main: fused GEMM (bf16 MFMA) + row argmax + loss reduction ----
__global__ __launch_bounds__(256, 2) void cluster_main(
    const float* __restrict__ feats,         // [N][128] fp32
    const unsigned short* __restrict__ chat, // [K][128] bf16
    const float* __restrict__ cnorm,         // [K] fp32
    float* __restrict__ out, int N) {

    __shared__ unsigned short As[BM * LSTR];   // 34816 B
    __shared__ unsigned short Bs[BN * LSTR];   // 34816 B
    __shared__ float nf_s[BM];                 // row sum-of-squares
    __shared__ float bv[2][BM];                // per-(wn,row) best value
    __shared__ int   bk[2][BM];                // per-(wn,row) best index

    const int tid  = threadIdx.x;
    const int lane = tid & 63;
    const int wave = tid >> 6;       // 0..3
    const int wm   = wave & 1;       // row half of 128x128 tile
    const int wn   = wave >> 1;      // col half
    const int m16  = lane & 15;      // intra-frag index
    const int quad = lane >> 4;      // 0..3

    // ---- Stage A tile (fp32 -> bf16) + fused row norms ----
    {
        const float4* src = (const float4*)(feats + (size_t)blockIdx.x * BM * D);
        #pragma unroll
        for (int s = 0; s < 16; ++s) {
            int f  = s * 256 + tid;      // float4 index, 0..4095
            int r  = f >> 5;             // row (32 float4 per row)
            int c4 = f & 31;
            float4 v = src[f];
            shortx4 pack;
            pack.x = (short)f32_to_bf16_rne(v.x);
            pack.y = (short)f32_to_bf16_rne(v.y);
            pack.z = (short)f32_to_bf16_rne(v.z);
            pack.w = (short)f32_to_bf16_rne(v.w);
            *(shortx4*)&As[r * LSTR + c4 * 4] = pack;
            // row-norm partial: 32 consecutive lanes share row r
            float sq = v.x * v.x + v.y * v.y + v.z * v.z + v.w * v.w;
            #pragma unroll
            for (int m = 1; m <= 16; m <<= 1) sq += __shfl_xor(sq, m);
            if ((tid & 31) == 0) nf_s[r] = sq;
        }
    }

    float best[16];
    int   bestk[16];
    #pragma unroll
    for (int s = 0; s < 16; ++s) { best[s] = -1e30f; bestk[s] = 0; }

    const int ktiles = 8;   // K=1024 / BN=128
    for (int t = 0; t < ktiles; ++t) {
        __syncthreads();   // previous compute done (and t=0: As/nf_s visible)
        // stage B tile: 128 centers x 128 bf16 = 32KB, b128 copies
        {
            const unsigned short* bsrc = chat + (size_t)t * BN * D;
            #pragma unroll
            for (int s = 0; s < 8; ++s) {
                int f = s * 256 + tid;   // 16B chunk index, 0..2047
                int r = f >> 4;          // center row (16 chunks/row)
                int c = f & 15;
                uint4 v = *(const uint4*)(bsrc + r * D + c * 8);
                *(uint4*)&Bs[r * LSTR + c * 8] = v;
            }
        }
        __syncthreads();

        floatx4 acc[4][4];
        #pragma unroll
        for (int i = 0; i < 4; ++i)
            #pragma unroll
            for (int j = 0; j < 4; ++j)
                acc[i][j] = (floatx4){0.f, 0.f, 0.f, 0.f};

        #pragma unroll
        for (int kk = 0; kk < 4; ++kk) {           // 4 k-steps of 32
            shortx8 a[4], b[4];
            #pragma unroll
            for (int i = 0; i < 4; ++i)
                a[i] = *(const shortx8*)&As[(wm * 64 + i * 16 + m16) * LSTR + kk * 32 + quad * 8];
            #pragma unroll
            for (int j = 0; j < 4; ++j)
                b[j] = *(const shortx8*)&Bs[(wn * 64 + j * 16 + m16) * LSTR + kk * 32 + quad * 8];
            #pragma unroll
            for (int i = 0; i < 4; ++i)
                #pragma unroll
                for (int j = 0; j < 4; ++j)
                    acc[i][j] = __builtin_amdgcn_mfma_f32_16x16x32_bf16(a[i], b[j], acc[i][j], 0, 0, 0);
        }

        // per-lane argmax update. C/D layout: col = lane&15, row = quad*4 + reg.
        // This lane owns cols (t*128 + wn*64 + 16j + m16), rows (wm*64 + 16i + quad*4 + r).
        const int colbase = t * BN + wn * 64 + m16;
        #pragma unroll
        for (int i = 0; i < 4; ++i) {
            #pragma unroll
            for (int r = 0; r < 4; ++r) {
                const int slot = i * 4 + r;
                #pragma unroll
                for (int j = 0; j < 4; ++j) {
                    float v = acc[i][j][r];
                    int   k = colbase + 16 * j;
                    if (v > best[slot] || (v == best[slot] && k < bestk[slot])) {
                        best[slot] = v; bestk[slot] = k;
                    }
                }
            }
        }
    }

    // cross-lane argmax within each wave: the 16 lanes differing in m16 hold
    // different cols of the SAME rows. Ties -> smaller index (argmax-first).
    #pragma unroll
    for (int mask = 1; mask <= 8; mask <<= 1) {
        #pragma unroll
        for (int s = 0; s < 16; ++s) {
            float ov = __shfl_xor(best[s], mask);
            int   ok = __shfl_xor(bestk[s], mask);
            if (ov > best[s] || (ov == best[s] && ok < bestk[s])) {
                best[s] = ov; bestk[s] = ok;
            }
        }
    }

    // spill per-wave winners: wave (wm,wn) owns rows wm*64..wm*64+63, col-half wn
    if (m16 == 0) {
        #pragma unroll
        for (int s = 0; s < 16; ++s) {
            int i = s >> 2, r = s & 3;
            int row = wm * 64 + 16 * i + quad * 4 + r;
            bv[wn][row] = best[s];
            bk[wn][row] = bestk[s];
        }
    }
    __syncthreads();

    // combine the two col-halves; one thread per row; then block reduction
    float lsum = 0.0f;
    if (tid < BM) {
        const int row = tid;
        float v0 = bv[0][row]; int k0 = bk[0][row];
        float v1 = bv[1][row]; int k1 = bk[1][row];
        bool take1 = (v1 > v0) || (v1 == v0 && k1 < k0);
        float d  = take1 ? v1 : v0;
        int   ka = take1 ? k1 : k0;
        float nf = fmaxf(sqrtf(nf_s[row]), 1e-12f);
        float na = cnorm[ka];
        lsum = 1.0f - 2.0f * d * na / nf + na * na;
    }
    // waves 0 and 1 hold the 128 row losses; reduce within each wave
    #pragma unroll
    for (int m = 1; m <= 32; m <<= 1) lsum += __shfl_xor(lsum, m);
    if (tid < BM && lane == 0) atomicAdd(out, lsum / (float)N);
}

extern "C" void kernel_launch(void* const* d_in, const int* in_sizes, int n_in,
                              void* d_out, int out_size, void* d_ws, size_t ws_size,
                              hipStream_t stream) {
    const float* feats   = (const float*)d_in[0];
    const float* centers = (const float*)d_in[1];
    const int N = in_sizes[0] / D;   // 131072
    const int K = in_sizes[1] / D;   // 1024

    unsigned short* chat = (unsigned short*)d_ws;                       // K*128 bf16 = 256 KB
    float* cnorm = (float*)((char*)d_ws + (size_t)K * D * sizeof(unsigned short)); // K fp32

    float* out = (float*)d_out;

    prep_centers<<<K, D, 0, stream>>>(centers, chat, cnorm, out);
    cluster_main<<<N / BM, 256, 0, stream>>>(feats, chat, cnorm, out, N);
}